// Round 8
// baseline (299.558 us; speedup 1.0000x reference)
//
#include <hip/hip_runtime.h>
#include <hip/hip_cooperative_groups.h>
namespace cg = cooperative_groups;

#define HH 192
#define WW 192
#define HW 36864          // 192*192
#define NPIX 2359296      // 64*192*192
#define NEG (-1.0e30f)

// ---------------- fused conv: p = sigmoid(conv(relu(conv(grid)+hb))+pb) ----------------
// Proven rounds 4-7.
__global__ __launch_bounds__(256) void k_conv_fused(const float* __restrict__ X,
                                                    const float* __restrict__ hw9,
                                                    const float* __restrict__ hb,
                                                    const float* __restrict__ pw9,
                                                    const float* __restrict__ pb,
                                                    float* __restrict__ p_out) {
  int idx = blockIdx.x * 256 + threadIdx.x;
  if (idx >= NPIX / 4) return;
  int b = idx / (HW / 4);
  int rem = idx - b * (HW / 4);
  int y = rem / 48;
  int ch = rem - y * 48;
  int x0 = ch * 4;
  const float* g = X + (size_t)b * (2 * HW);  // grid = channel 0

  float gr[5][8];
#pragma unroll
  for (int ry = 0; ry < 5; ++ry) {
    int yy = y - 2 + ry;
    if (yy < 0 || yy >= HH) {
#pragma unroll
      for (int j = 0; j < 8; ++j) gr[ry][j] = 0.f;
    } else {
      const float* row = g + yy * WW;
      float4 a = (x0 >= 4) ? *(const float4*)(row + x0 - 4) : make_float4(0, 0, 0, 0);
      float4 m = *(const float4*)(row + x0);
      float4 cq = (x0 + 4 < WW) ? *(const float4*)(row + x0 + 4) : make_float4(0, 0, 0, 0);
      gr[ry][0] = a.z; gr[ry][1] = a.w;
      gr[ry][2] = m.x; gr[ry][3] = m.y; gr[ry][4] = m.z; gr[ry][5] = m.w;
      gr[ry][6] = cq.x; gr[ry][7] = cq.y;
    }
  }
  float hwv[9], pwv[9];
#pragma unroll
  for (int i = 0; i < 9; ++i) { hwv[i] = hw9[i]; pwv[i] = pw9[i]; }
  float hbv = hb[0], pbv = pb[0];

  float hr[3][6];
#pragma unroll
  for (int ry = 0; ry < 3; ++ry) {
    int yy = y - 1 + ry;
    bool rowok = (yy >= 0 && yy < HH);
#pragma unroll
    for (int j = 0; j < 6; ++j) {
      int xx = x0 - 1 + j;
      float acc = hbv;
#pragma unroll
      for (int di = 0; di < 3; ++di)
#pragma unroll
        for (int dj = 0; dj < 3; ++dj)
          acc = fmaf(gr[ry + di][j + dj], hwv[di * 3 + dj], acc);
      hr[ry][j] = (rowok && xx >= 0 && xx < WW) ? fmaxf(acc, 0.f) : 0.f;
    }
  }
  float o[4];
#pragma unroll
  for (int k = 0; k < 4; ++k) {
    float acc = pbv;
#pragma unroll
    for (int di = 0; di < 3; ++di)
#pragma unroll
      for (int dj = 0; dj < 3; ++dj)
        acc = fmaf(hr[di][k + dj], pwv[di * 3 + dj], acc);
    o[k] = 1.f / (1.f + __expf(-acc));
  }
  *(float4*)(p_out + (size_t)b * HW + y * WW + x0) = make_float4(o[0], o[1], o[2], o[3]);
}

// 7-iteration tile body (proven rounds 4-7), all indices compile-time constant.
#define ITER7_BODY                                                                   \
  _Pragma("unroll 1")                                                                \
  for (int it = 0; it < 7; ++it) {                                                   \
    float th[8], bh[8];                                                              \
    _Pragma("unroll")                                                                \
    for (int j = 0; j < 8; ++j) { float s = __shfl(v[7][j], lup, 64); th[j] = (ly == 0) ? NEG : s; } \
    _Pragma("unroll")                                                                \
    for (int j = 0; j < 8; ++j) { float s = __shfl(v[0][j], ldn, 64); bh[j] = (ly == 7) ? NEG : s; } \
    float vm[8][8];                                                                  \
    _Pragma("unroll")                                                                \
    for (int r = 0; r < 8; ++r) {                                                    \
      _Pragma("unroll")                                                              \
      for (int j = 0; j < 8; ++j) {                                                  \
        float up = (r == 0) ? th[j] : v[r - 1][j];                                   \
        float dn = (r == 7) ? bh[j] : v[r + 1][j];                                   \
        vm[r][j] = fmaxf(fmaxf(up, dn), v[r][j]);                                    \
      }                                                                              \
    }                                                                                \
    _Pragma("unroll")                                                                \
    for (int r = 0; r < 8; ++r) {                                                    \
      float sl = __shfl(vm[r][7], llt, 64);                                          \
      float sr = __shfl(vm[r][0], lrt, 64);                                          \
      float lvm = (lx == 0) ? NEG : sl;                                              \
      float rvm = (lx == 7) ? NEG : sr;                                              \
      float hm0 = fmaxf(lvm, fmaxf(vm[r][0], vm[r][1]));                             \
      float hm7 = fmaxf(vm[r][6], fmaxf(vm[r][7], rvm));                             \
      v[r][0] = fmaxf(v[r][0], fmaf(p[r][0], hm0, c[r][0]));                         \
      _Pragma("unroll")                                                              \
      for (int j = 1; j < 7; ++j) {                                                  \
        float hm = fmaxf(vm[r][j - 1], fmaxf(vm[r][j], vm[r][j + 1]));               \
        v[r][j] = fmaxf(v[r][j], fmaf(p[r][j], hm, c[r][j]));                        \
      }                                                                              \
      v[r][7] = fmaxf(v[r][7], fmaf(p[r][7], hm7, c[r][7]));                         \
    }                                                                                \
  }

#define SPREAD8(dst_row, t0, t1)                                                     \
  dst_row[0] = t0.x; dst_row[1] = t0.y; dst_row[2] = t0.z; dst_row[3] = t0.w;        \
  dst_row[4] = t1.x; dst_row[5] = t1.y; dst_row[6] = t1.z; dst_row[7] = t1.w;

// Opaque pin: forces p/c values to live in VGPRs and makes reload-remat illegal.
#define PIN_PC                                                                       \
  _Pragma("unroll")                                                                  \
  for (int r = 0; r < 8; ++r) {                                                      \
    _Pragma("unroll")                                                                \
    for (int j = 0; j < 8; ++j) {                                                    \
      asm volatile("" : "+v"(p[r][j]), "+v"(c[r][j]));                               \
    }                                                                                \
  }

// ---------------- cooperative all-35-iteration kernel ----------------
__global__ __launch_bounds__(256, 1) __attribute__((amdgpu_waves_per_eu(1, 1)))
void k_vi(const float* __restrict__ p_glob,
          const float* __restrict__ X,
          float* __restrict__ out_v,
          float* __restrict__ bufA,
          float* __restrict__ bufB) {
  cg::grid_group grid = cg::this_grid();
  int wid = blockIdx.x * 4 + (threadIdx.x >> 6);
  int lane = threadIdx.x & 63;
  int b = wid >> 4;
  int t = wid & 15;
  int ti = t >> 2, tj = t & 3;
  int ly = lane >> 3, lx = lane & 7;
  int py = ti * 48 - 8 + ly * 8;
  int px = tj * 48 - 8 + lx * 8;
  bool colok = (px >= 0 && px < WW);

  const float* gimg = X + (size_t)b * (2 * HW) + HW;
  const float* pimg = p_glob + (size_t)b * HW;

  float v[8][8], p[8][8], c[8][8];
#pragma unroll
  for (int r = 0; r < 8; ++r) {
    int gy = py + r;
    if (colok && gy >= 0 && gy < HH) {
      const float* pp = pimg + gy * WW + px;
      const float* gp = gimg + gy * WW + px;
      float4 tp0 = *(const float4*)(pp);
      float4 tp1 = *(const float4*)(pp + 4);
      float4 tg0 = *(const float4*)(gp);
      float4 tg1 = *(const float4*)(gp + 4);
      SPREAD8(p[r], tp0, tp1);
      float gg[8];
      SPREAD8(gg, tg0, tg1);
#pragma unroll
      for (int j = 0; j < 8; ++j) {
        v[r][j] = gg[j] - 1.f;
        c[r][j] = (gg[j] - 1.f) * (1.f - p[r][j]);
      }
    } else {
#pragma unroll
      for (int j = 0; j < 8; ++j) { v[r][j] = NEG; p[r][j] = 0.f; c[r][j] = NEG; }
    }
  }

  PIN_PC

  int lup = (lane - 8) & 63, ldn = (lane + 8) & 63;
  int llt = (lane - 1) & 63, lrt = (lane + 1) & 63;

  for (int span = 0; span < 5; ++span) {
    ITER7_BODY

    float* wb = (span == 4) ? out_v : ((span & 1) ? bufB : bufA);
    float* wimg = wb + (size_t)b * HW;
    if (ly >= 1 && ly <= 6 && lx >= 1 && lx <= 6) {
#pragma unroll
      for (int r = 0; r < 8; ++r) {
        *(float4*)(wimg + (py + r) * WW + px) = make_float4(v[r][0], v[r][1], v[r][2], v[r][3]);
        *(float4*)(wimg + (py + r) * WW + px + 4) = make_float4(v[r][4], v[r][5], v[r][6], v[r][7]);
      }
    }
    if (span < 4) {
      grid.sync();
      if (ly == 0 || ly == 7 || lx == 0 || lx == 7) {
#pragma unroll
        for (int r = 0; r < 8; ++r) {
          int gy = py + r;
          if (colok && gy >= 0 && gy < HH) {
            float4 a = *(const float4*)(wimg + gy * WW + px);
            float4 d = *(const float4*)(wimg + gy * WW + px + 4);
            SPREAD8(v[r], a, d);
          }
          // OOB entries stay NEG (p=0, c=NEG pin them at NEG)
        }
      }
    }
  }
}

// ---------------- fallback span kernel (same fixes) ----------------
template <int FIRST>
__global__ __launch_bounds__(256, 1) __attribute__((amdgpu_waves_per_eu(1, 1)))
void k_span(const float* __restrict__ v_in,
            const float* __restrict__ p_glob,
            const float* __restrict__ X,
            float* __restrict__ v_out) {
  int wid = blockIdx.x * 4 + (threadIdx.x >> 6);
  int lane = threadIdx.x & 63;
  int b = wid >> 4;
  int t = wid & 15;
  int ti = t >> 2, tj = t & 3;
  int ly = lane >> 3, lx = lane & 7;
  int py = ti * 48 - 8 + ly * 8;
  int px = tj * 48 - 8 + lx * 8;
  bool colok = (px >= 0 && px < WW);

  const float* gimg = X + (size_t)b * (2 * HW) + HW;
  const float* pimg = p_glob + (size_t)b * HW;
  const float* vimg = v_in + (size_t)b * HW;

  float v[8][8], p[8][8], c[8][8];
#pragma unroll
  for (int r = 0; r < 8; ++r) {
    int gy = py + r;
    if (colok && gy >= 0 && gy < HH) {
      const float* pp = pimg + gy * WW + px;
      const float* gp = gimg + gy * WW + px;
      float4 tp0 = *(const float4*)(pp);
      float4 tp1 = *(const float4*)(pp + 4);
      float4 tg0 = *(const float4*)(gp);
      float4 tg1 = *(const float4*)(gp + 4);
      SPREAD8(p[r], tp0, tp1);
      float gg[8];
      SPREAD8(gg, tg0, tg1);
      if (FIRST) {
#pragma unroll
        for (int j = 0; j < 8; ++j) v[r][j] = gg[j] - 1.f;
      } else {
        const float* vp = vimg + gy * WW + px;
        float4 tv0 = *(const float4*)(vp);
        float4 tv1 = *(const float4*)(vp + 4);
        SPREAD8(v[r], tv0, tv1);
      }
#pragma unroll
      for (int j = 0; j < 8; ++j)
        c[r][j] = (gg[j] - 1.f) * (1.f - p[r][j]);
    } else {
#pragma unroll
      for (int j = 0; j < 8; ++j) { v[r][j] = NEG; p[r][j] = 0.f; c[r][j] = NEG; }
    }
  }

  PIN_PC

  int lup = (lane - 8) & 63, ldn = (lane + 8) & 63;
  int llt = (lane - 1) & 63, lrt = (lane + 1) & 63;

  ITER7_BODY

  if (ly >= 1 && ly <= 6 && lx >= 1 && lx <= 6) {
    float* wimg = v_out + (size_t)b * HW;
#pragma unroll
    for (int r = 0; r < 8; ++r) {
      *(float4*)(wimg + (py + r) * WW + px) = make_float4(v[r][0], v[r][1], v[r][2], v[r][3]);
      *(float4*)(wimg + (py + r) * WW + px + 4) = make_float4(v[r][4], v[r][5], v[r][6], v[r][7]);
    }
  }
}

// ---------------- launch ----------------
extern "C" void kernel_launch(void* const* d_in, const int* in_sizes, int n_in,
                              void* d_out, int out_size, void* d_ws, size_t ws_size,
                              hipStream_t stream) {
  const float* X = (const float*)d_in[0];
  const float* hp_w = (const float*)d_in[1];
  const float* hp_b = (const float*)d_in[2];
  const float* p_w = (const float*)d_in[3];
  const float* p_b = (const float*)d_in[4];

  float* out = (float*)d_out;
  float* out_v = out;          // NPIX floats (final v)
  float* out_p = out + NPIX;   // NPIX floats (p)
  float* bufA = (float*)d_ws;  // NPIX floats
  float* bufB = bufA + NPIX;   // NPIX floats

  int nblk = (NPIX / 4 + 255) / 256;
  k_conv_fused<<<nblk, 256, 0, stream>>>(X, hp_w, hp_b, p_w, p_b, out_p);

  const float* p_c = out_p;
  void* args[] = { (void*)&p_c, (void*)&X, (void*)&out_v, (void*)&bufA, (void*)&bufB };
  hipError_t e = hipLaunchCooperativeKernel((const void*)k_vi, dim3(256), dim3(256),
                                            args, 0, stream);
  if (e != hipSuccess) {
    (void)hipGetLastError();  // clear sticky error; proven fallback chain
    k_span<1><<<256, 256, 0, stream>>>(X /*unused*/, out_p, X, out_v);
    k_span<0><<<256, 256, 0, stream>>>(out_v, out_p, X, bufA);
    k_span<0><<<256, 256, 0, stream>>>(bufA, out_p, X, out_v);
    k_span<0><<<256, 256, 0, stream>>>(out_v, out_p, X, bufA);
    k_span<0><<<256, 256, 0, stream>>>(bufA, out_p, X, out_v);
  }
}

// Round 10
// 138.028 us; speedup vs baseline: 2.1703x; 2.1703x over previous
//
#include <hip/hip_runtime.h>

#define HH 192
#define WW 192
#define HW 36864          // 192*192
#define NPIX 2359296      // 64*192*192
#define NEG (-1.0e30f)
#define RPW 15            // rows per wave
#define HALO 36           // >= 35 iterations of 1-row/iter contamination

// One block = (image b, strip s). Strip s clean rows: [48s, 48s+48).
// Window = [48s-36, 48s+84): 120 rows. 8 waves x 15 rows; lane owns 3 cols
// (col0 = 3*lane). v/p/c in registers (135 floats). Zero inter-block comm:
// halo absorbs all 35 iterations. 1 barrier/iter (wave-boundary rows via LDS).
__global__ __launch_bounds__(512, 2)
void k_mvprop(const float* __restrict__ X,
              const float* __restrict__ hw9p, const float* __restrict__ hbp,
              const float* __restrict__ pw9p, const float* __restrict__ pbp,
              float* __restrict__ out_v, float* __restrict__ out_p) {
  __shared__ float lds_x[2][8][2][WW];   // [parity][wave][top/bot][col] 24.6KB

  const int blk = blockIdx.x;
  const int b = blk >> 2;
  const int s = blk & 3;
  const int w = threadIdx.x >> 6;
  const int lane = threadIdx.x & 63;
  const int col0 = lane * 3;
  const int grow0 = s * 48 - HALO + w * RPW;   // global row of wave-local row 0

  const float* gridp = X + (size_t)b * (2 * HW);
  const float* goalp = gridp + HW;

  float hw[9], pw[9];
#pragma unroll
  for (int i = 0; i < 9; ++i) { hw[i] = hw9p[i]; pw[i] = pw9p[i]; }
  const float hb = hbp[0], pb = pbp[0];

  // ---- fused conv (rolling window, FULLY unrolled => all indices static) ----
  float v_[RPW][3], p_[RPW][3], c_[RPW][3];
  {
    float ga[7], gb2[7], gc[7], ha[5], hb2[5], hc[5];
#pragma unroll
    for (int j = 0; j < 7; ++j) { ga[j] = gb2[j] = gc[j] = 0.f; }
#pragma unroll
    for (int j = 0; j < 5; ++j) { ha[j] = hb2[j] = hc[j] = 0.f; }
#pragma unroll
    for (int t = 0; t < RPW + 4; ++t) {
      int grow = grow0 - 2 + t;
#pragma unroll
      for (int j = 0; j < 7; ++j) { ga[j] = gb2[j]; gb2[j] = gc[j]; }
      if (grow >= 0 && grow < HH) {
        const float* rp = gridp + grow * WW;
#pragma unroll
        for (int j = 0; j < 7; ++j) {
          int cc = col0 - 2 + j;
          gc[j] = (cc >= 0 && cc < WW) ? rp[cc] : 0.f;
        }
      } else {
#pragma unroll
        for (int j = 0; j < 7; ++j) gc[j] = 0.f;
      }
      if (t >= 2) {
        int hrow = grow0 - 3 + t;
        bool hrok = (hrow >= 0 && hrow < HH);
#pragma unroll
        for (int j = 0; j < 5; ++j) { ha[j] = hb2[j]; hb2[j] = hc[j]; }
#pragma unroll
        for (int j = 0; j < 5; ++j) {
          int hcol = col0 - 1 + j;
          float acc = hb;
#pragma unroll
          for (int dj = 0; dj < 3; ++dj) {
            acc = fmaf(ga[j + dj], hw[0 + dj], acc);
            acc = fmaf(gb2[j + dj], hw[3 + dj], acc);
            acc = fmaf(gc[j + dj], hw[6 + dj], acc);
          }
          hc[j] = (hrok && hcol >= 0 && hcol < WW) ? fmaxf(acc, 0.f) : 0.f;
        }
      }
      if (t >= 4) {
        int r = t - 4;                       // static under full unroll
        int prow = grow0 + r;
        if (prow >= 0 && prow < HH) {
          const float* glr = goalp + prow * WW;
#pragma unroll
          for (int j = 0; j < 3; ++j) {
            float z = pb;
#pragma unroll
            for (int dj = 0; dj < 3; ++dj) {
              z = fmaf(ha[j + dj], pw[0 + dj], z);
              z = fmaf(hb2[j + dj], pw[3 + dj], z);
              z = fmaf(hc[j + dj], pw[6 + dj], z);
            }
            float pv = 1.f / (1.f + __expf(-z));
            float gl = glr[col0 + j];
            p_[r][j] = pv;
            v_[r][j] = gl - 1.f;
            c_[r][j] = (gl - 1.f) * (1.f - pv);
          }
        } else {
#pragma unroll
          for (int j = 0; j < 3; ++j) { p_[r][j] = 0.f; v_[r][j] = NEG; c_[r][j] = NEG; }
        }
      }
    }
  }

  // ---- 35 value iterations, 1 barrier each ----
  const int llt = (lane - 1) & 63, lrt = (lane + 1) & 63;
  int par = 0;

#pragma unroll 1
  for (int it = 0; it < 35; ++it) {
#pragma unroll
    for (int j = 0; j < 3; ++j) {
      lds_x[par][w][0][col0 + j] = v_[0][j];
      lds_x[par][w][1][col0 + j] = v_[RPW - 1][j];
    }
    __syncthreads();
    float vt0 = (w > 0) ? lds_x[par][w - 1][1][col0 + 0] : NEG;
    float vt1 = (w > 0) ? lds_x[par][w - 1][1][col0 + 1] : NEG;
    float vt2 = (w > 0) ? lds_x[par][w - 1][1][col0 + 2] : NEG;
    float vb0 = (w < 7) ? lds_x[par][w + 1][0][col0 + 0] : NEG;
    float vb1 = (w < 7) ? lds_x[par][w + 1][0][col0 + 1] : NEG;
    float vb2 = (w < 7) ? lds_x[par][w + 1][0][col0 + 2] : NEG;
    par ^= 1;

    float pr0 = vt0, pr1 = vt1, pr2 = vt2;
#pragma unroll
    for (int r = 0; r < RPW; ++r) {
      float nx0 = (r < RPW - 1) ? v_[r + 1][0] : vb0;
      float nx1 = (r < RPW - 1) ? v_[r + 1][1] : vb1;
      float nx2 = (r < RPW - 1) ? v_[r + 1][2] : vb2;
      float vm0 = fmaxf(fmaxf(pr0, v_[r][0]), nx0);
      float vm1 = fmaxf(fmaxf(pr1, v_[r][1]), nx1);
      float vm2 = fmaxf(fmaxf(pr2, v_[r][2]), nx2);
      float lvm = __shfl(vm2, llt, 64);
      float rvm = __shfl(vm0, lrt, 64);
      if (lane == 0) lvm = NEG;     // true image left edge (-inf pad)
      if (lane == 63) rvm = NEG;    // true image right edge
      float hm0 = fmaxf(lvm, fmaxf(vm0, vm1));
      float hm1 = fmaxf(vm0, fmaxf(vm1, vm2));
      float hm2 = fmaxf(vm1, fmaxf(vm2, rvm));
      float o0 = v_[r][0], o1 = v_[r][1], o2 = v_[r][2];
      v_[r][0] = fmaxf(o0, fmaf(p_[r][0], hm0, c_[r][0]));
      v_[r][1] = fmaxf(o1, fmaf(p_[r][1], hm1, c_[r][1]));
      v_[r][2] = fmaxf(o2, fmaf(p_[r][2], hm2, c_[r][2]));
      pr0 = o0; pr1 = o1; pr2 = o2;
    }
  }

  // ---- store clean rows (per-row guard; scalar stores, contiguous per wave) ----
  const int cr0 = s * 48, cr1 = s * 48 + 48;
  float* vout = out_v + (size_t)b * HW;
  float* pout = out_p + (size_t)b * HW;
#pragma unroll
  for (int r = 0; r < RPW; ++r) {
    int grow = grow0 + r;
    if (grow >= cr0 && grow < cr1) {
#pragma unroll
      for (int j = 0; j < 3; ++j) {
        vout[grow * WW + col0 + j] = v_[r][j];
        pout[grow * WW + col0 + j] = p_[r][j];
      }
    }
  }
}

// ---------------- launch: ONE kernel, no workspace, no cooperative ----------------
extern "C" void kernel_launch(void* const* d_in, const int* in_sizes, int n_in,
                              void* d_out, int out_size, void* d_ws, size_t ws_size,
                              hipStream_t stream) {
  const float* X = (const float*)d_in[0];
  const float* hp_w = (const float*)d_in[1];
  const float* hp_b = (const float*)d_in[2];
  const float* p_w = (const float*)d_in[3];
  const float* p_b = (const float*)d_in[4];

  float* out = (float*)d_out;
  float* out_v = out;
  float* out_p = out + NPIX;

  k_mvprop<<<256, 512, 0, stream>>>(X, hp_w, hp_b, p_w, p_b, out_v, out_p);
}